// Round 5
// baseline (466.958 us; speedup 1.0000x reference)
//
#include <hip/hip_runtime.h>
#include <hip/hip_fp16.h>

// DGConv: K=2 diffusion steps of x <- (1-d)x + d * (D^-1/2 (A+I) D^-1/2) x, then x @ W + b.
// N=100000, E=1600000, D=64. delta = 5.27/2 = 2.635.
//
// z = dinv (.) x stored fp16: row = 128B = one cache line. SpMM gathers z-rows.
// Lane layout in spmm: 32 lanes per row (half2/lane), 2 edges per VMEM instruction.
// xi is recovered as z[i]*rdeg[i] (rdeg = 1/dinv), so only z-streams are kept.

#define TPB 256
#define SCAN_T 256
#define SCAN_I 4
#define SCAN_CHUNK (SCAN_T * SCAN_I)
#define BATCH 16            // VMEM instrs in flight per wave = 2*BATCH edges

__global__ void count_kernel(const int* __restrict__ dst, int* __restrict__ counts, int e) {
    int i = blockIdx.x * blockDim.x + threadIdx.x;
    if (i < e) atomicAdd(&counts[dst[i]], 1);
}

__global__ void scan_partials(const int* __restrict__ counts, int* __restrict__ bsums, int n) {
    __shared__ int red[SCAN_T];
    int t = threadIdx.x;
    int base = blockIdx.x * SCAN_CHUNK + t * SCAN_I;
    int s = 0;
#pragma unroll
    for (int k = 0; k < SCAN_I; ++k) { int i = base + k; if (i < n) s += counts[i]; }
    red[t] = s;
    __syncthreads();
    for (int off = SCAN_T / 2; off > 0; off >>= 1) {
        if (t < off) red[t] += red[t + off];
        __syncthreads();
    }
    if (t == 0) bsums[blockIdx.x] = red[0];
}

__global__ void scan_bsums(int* __restrict__ bsums, int nb, int* __restrict__ row_ptr,
                           int n, int e) {
    __shared__ int s[512];
    int t = threadIdx.x;
    int v = (t < nb) ? bsums[t] : 0;
    s[t] = v;
    __syncthreads();
    for (int off = 1; off < 512; off <<= 1) {
        int a = (t >= off) ? s[t - off] : 0;
        __syncthreads();
        s[t] += a;
        __syncthreads();
    }
    if (t < nb) bsums[t] = s[t] - v;
    if (t == 0) row_ptr[n] = e;
}

__global__ void scan_emit(const int* __restrict__ counts, const int* __restrict__ boffs,
                          int* __restrict__ row_ptr, int* __restrict__ cursor,
                          float* __restrict__ dinv, float* __restrict__ rdeg, int n) {
    __shared__ int red[SCAN_T];
    int t = threadIdx.x;
    int base = blockIdx.x * SCAN_CHUNK + t * SCAN_I;
    int c[SCAN_I];
    int s = 0;
#pragma unroll
    for (int k = 0; k < SCAN_I; ++k) { int i = base + k; c[k] = (i < n) ? counts[i] : 0; s += c[k]; }
    red[t] = s;
    __syncthreads();
    for (int off = 1; off < SCAN_T; off <<= 1) {
        int a = (t >= off) ? red[t - off] : 0;
        __syncthreads();
        red[t] += a;
        __syncthreads();
    }
    int run = boffs[blockIdx.x] + red[t] - s;
#pragma unroll
    for (int k = 0; k < SCAN_I; ++k) {
        int i = base + k;
        if (i < n) {
            row_ptr[i] = run;
            cursor[i]  = run;
            float d = (float)(c[k] + 1);
            dinv[i] = rsqrtf(d);
            rdeg[i] = sqrtf(d);
            run += c[k];
        }
    }
}

// zh = fp16(dinv * x), vectorized 4 elems/thread; zero row n of zh and z1h.
__global__ void cast_z(const float* __restrict__ x, const float* __restrict__ dinv,
                       __half* __restrict__ zh, __half* __restrict__ z1h, int n) {
    int i = blockIdx.x * blockDim.x + threadIdx.x;   // one group of 4 features
    int total = n * 16;
    if (i < total) {
        float4 v = reinterpret_cast<const float4*>(x)[i];
        float dv = dinv[i >> 4];
        __half2 a, b2;
        a.x  = __float2half(v.x * dv); a.y  = __float2half(v.y * dv);
        b2.x = __float2half(v.z * dv); b2.y = __float2half(v.w * dv);
        reinterpret_cast<__half2*>(zh)[2 * i]     = a;
        reinterpret_cast<__half2*>(zh)[2 * i + 1] = b2;
    } else if (i < total + 16) {
        __half2 z; z.x = __float2half(0.f); z.y = __float2half(0.f);
        reinterpret_cast<__half2*>(zh)[2 * i]      = z;
        reinterpret_cast<__half2*>(zh)[2 * i + 1]  = z;
        reinterpret_cast<__half2*>(z1h)[2 * i]     = z;
        reinterpret_cast<__half2*>(z1h)[2 * i + 1] = z;
    }
}

__global__ void fill_kernel(const int* __restrict__ src, const int* __restrict__ dst,
                            int* __restrict__ cursor, int* __restrict__ col, int e) {
    int i = blockIdx.x * blockDim.x + threadIdx.x;
    if (i >= e) return;
    int pos = atomicAdd(&cursor[dst[i]], 1);
    col[pos] = src[i];
}

// 32 lanes per row, half2 per lane; lanes 0-31 take even edges, 32-63 odd edges.
// BATCH instrs in flight = 2*BATCH edges. Tail clamps to zero row `nzero`.
__device__ __forceinline__ float2 spmm_row2(const __half* __restrict__ zh,
                                            const int* __restrict__ col,
                                            int beg, int end, int sub, int m, int nzero) {
    float a0 = 0.f, a1 = 0.f;
    for (int j = beg; j < end; j += 2 * BATCH) {
        int c[BATCH];
#pragma unroll
        for (int k = 0; k < BATCH; ++k) {
            int e = j + 2 * k + sub;
            int cc = col[min(e, end - 1)];        // unconditional in-bounds load
            c[k] = (e < end) ? cc : nzero;
        }
        __half2 v[BATCH];
#pragma unroll
        for (int k = 0; k < BATCH; ++k)
            v[k] = *reinterpret_cast<const __half2*>(zh + (size_t)(unsigned)c[k] * 64u + 2u * (unsigned)m);
#pragma unroll
        for (int k = 0; k < BATCH; ++k) {
            float2 f = __half22float2(v[k]);
            a0 += f.x; a1 += f.y;
        }
    }
    a0 += __shfl_xor(a0, 32);    // merge even/odd edge partials
    a1 += __shfl_xor(a1, 32);
    return make_float2(a0, a1);
}

// Step 1: zh -> z1h (= dinv * x1). xi recovered as zh[i]*rdeg.
__global__ void spmm1_kernel(const __half* __restrict__ zh, __half* __restrict__ z1h,
                             const int* __restrict__ row_ptr, const int* __restrict__ col,
                             const float* __restrict__ dinv, const float* __restrict__ rdeg,
                             int n, float delta) {
    int node = blockIdx.x * (blockDim.x >> 6) + (threadIdx.x >> 6);
    int lane = threadIdx.x & 63;
    if (node >= n) return;
    int sub = lane >> 5, m = lane & 31;
    float dv = dinv[node], rd = rdeg[node];
    float2 acc = spmm_row2(zh, col, row_ptr[node], row_ptr[node + 1], sub, m, n);
    __half2 zp = *reinterpret_cast<const __half2*>(zh + (size_t)node * 64 + 2 * m);
    float2 zf = __half22float2(zp);                     // zf = dv * xi
    float x1x = (1.f - delta) * (zf.x * rd) + delta * dv * (zf.x + acc.x);
    float x1y = (1.f - delta) * (zf.y * rd) + delta * dv * (zf.y + acc.y);
    if (sub == 0) {
        __half2 o; o.x = __float2half(dv * x1x); o.y = __float2half(dv * x1y);
        *reinterpret_cast<__half2*>(z1h + (size_t)node * 64 + 2 * m) = o;
    }
}

// Step 2 SpMM + y = x2 @ W + b. res held 2 features/lane; shfl-broadcast GEMM.
__global__ void spmm2_gemm_kernel(const __half* __restrict__ z1h, float* __restrict__ y,
                                  const int* __restrict__ row_ptr, const int* __restrict__ col,
                                  const float* __restrict__ dinv, const float* __restrict__ rdeg,
                                  const float* __restrict__ W, const float* __restrict__ b,
                                  int n, float delta) {
    __shared__ float Ws[64 * 64];
    __shared__ float bs[64];
    for (int i = threadIdx.x; i < 64 * 64; i += blockDim.x) Ws[i] = W[i];
    if (threadIdx.x < 64) bs[threadIdx.x] = b[threadIdx.x];
    __syncthreads();
    int node = blockIdx.x * (blockDim.x >> 6) + (threadIdx.x >> 6);
    int lane = threadIdx.x & 63;
    if (node >= n) return;
    int sub = lane >> 5, m = lane & 31;
    float dv = dinv[node], rd = rdeg[node];
    float2 acc = spmm_row2(z1h, col, row_ptr[node], row_ptr[node + 1], sub, m, n);
    __half2 zp = *reinterpret_cast<const __half2*>(z1h + (size_t)node * 64 + 2 * m);
    float2 zf = __half22float2(zp);
    float rx = (1.f - delta) * (zf.x * rd) + delta * dv * (zf.x + acc.x);  // res[2m]
    float ry = (1.f - delta) * (zf.y * rd) + delta * dv * (zf.y + acc.y);  // res[2m+1]
    float o0 = bs[2 * m], o1 = bs[2 * m + 1];
#pragma unroll
    for (int q = 0; q < 32; ++q) {
        float ax = __shfl(rx, q);          // res[2q]
        float ay = __shfl(ry, q);          // res[2q+1]
        o0 = fmaf(ax, Ws[(2 * q) * 64 + 2 * m], o0);
        o0 = fmaf(ay, Ws[(2 * q + 1) * 64 + 2 * m], o0);
        o1 = fmaf(ax, Ws[(2 * q) * 64 + 2 * m + 1], o1);
        o1 = fmaf(ay, Ws[(2 * q + 1) * 64 + 2 * m + 1], o1);
    }
    if (sub == 0) {
        *reinterpret_cast<float2*>(y + (size_t)node * 64 + 2 * m) = make_float2(o0, o1);
    }
}

extern "C" void kernel_launch(void* const* d_in, const int* in_sizes, int n_in,
                              void* d_out, int out_size, void* d_ws, size_t ws_size,
                              hipStream_t stream) {
    const float* x  = (const float*)d_in[0];
    const int*   ei = (const int*)d_in[1];   // [2, E]: src then dst
    const float* W  = (const float*)d_in[2];
    const float* b  = (const float*)d_in[3];
    float* out = (float*)d_out;

    const int N = in_sizes[0] / 64;
    const int E = in_sizes[1] / 2;
    const float delta = (float)(5.27 / 2.0);

    char* p = (char*)d_ws;
    __half* zh   = (__half*)p;  p += (size_t)(N + 1) * 64 * sizeof(__half);
    __half* z1h  = (__half*)p;  p += (size_t)(N + 1) * 64 * sizeof(__half);
    int*   col   = (int*)p;     p += ((size_t)E + 64) * sizeof(int);
    float* dinv  = (float*)p;   p += (size_t)N * sizeof(float);
    float* rdeg  = (float*)p;   p += (size_t)N * sizeof(float);
    int*   counts= (int*)p;     p += (size_t)N * sizeof(int);
    int*   rowp  = (int*)p;     p += (size_t)(N + 4) * sizeof(int);
    int*   cursor= (int*)p;     p += (size_t)N * sizeof(int);
    int*   bsums = (int*)p;     p += 512 * sizeof(int);

    hipMemsetAsync(counts, 0, (size_t)N * sizeof(int), stream);

    int grid_e = (E + TPB - 1) / TPB;
    int grid_n = (N + (TPB / 64) - 1) / (TPB / 64);
    int nb_scan = (N + SCAN_CHUNK - 1) / SCAN_CHUNK;
    int grid_c = (N * 16 + 16 + TPB - 1) / TPB;

    count_kernel<<<grid_e, TPB, 0, stream>>>(ei + E, counts, E);
    scan_partials<<<nb_scan, SCAN_T, 0, stream>>>(counts, bsums, N);
    scan_bsums<<<1, 512, 0, stream>>>(bsums, nb_scan, rowp, N, E);
    scan_emit<<<nb_scan, SCAN_T, 0, stream>>>(counts, bsums, rowp, cursor, dinv, rdeg, N);
    cast_z<<<grid_c, TPB, 0, stream>>>(x, dinv, zh, z1h, N);
    fill_kernel<<<grid_e, TPB, 0, stream>>>(ei, ei + E, cursor, col, E);

    spmm1_kernel<<<grid_n, TPB, 0, stream>>>(zh, z1h, rowp, col, dinv, rdeg, N, delta);
    spmm2_gemm_kernel<<<grid_n, TPB, 0, stream>>>(z1h, out, rowp, col, dinv, rdeg, W, b, N, delta);
}

// Round 6
// 413.100 us; speedup vs baseline: 1.1304x; 1.1304x over previous
//
#include <hip/hip_runtime.h>
#include <hip/hip_fp16.h>

// DGConv: K=2 diffusion steps of x <- (1-d)x + d * (D^-1/2 (A+I) D^-1/2) x, then x @ W + b.
// N=100000, E=1600000, D=64. delta = 5.27/2 = 2.635.
//
// z = dinv (.) x stored fp16: row = 128B = one cache line; SpMM gathers whole rows
// (64 lanes x 2B). Only z-streams are kept: xi is recovered as z[i]*rdeg[i].
// Row gathers are non-temporal (no L1 allocate) - random one-shot lines.

#define TPB 256
#define SCAN_T 256
#define SCAN_I 4
#define SCAN_CHUNK (SCAN_T * SCAN_I)
#define BATCH 16

__global__ void count_kernel(const int* __restrict__ dst, int* __restrict__ counts, int e) {
    int i = blockIdx.x * blockDim.x + threadIdx.x;
    if (i < e) atomicAdd(&counts[dst[i]], 1);
}

__global__ void scan_partials(const int* __restrict__ counts, int* __restrict__ bsums, int n) {
    __shared__ int red[SCAN_T];
    int t = threadIdx.x;
    int base = blockIdx.x * SCAN_CHUNK + t * SCAN_I;
    int s = 0;
#pragma unroll
    for (int k = 0; k < SCAN_I; ++k) { int i = base + k; if (i < n) s += counts[i]; }
    red[t] = s;
    __syncthreads();
    for (int off = SCAN_T / 2; off > 0; off >>= 1) {
        if (t < off) red[t] += red[t + off];
        __syncthreads();
    }
    if (t == 0) bsums[blockIdx.x] = red[0];
}

__global__ void scan_bsums(int* __restrict__ bsums, int nb, int* __restrict__ row_ptr,
                           int n, int e) {
    __shared__ int s[512];
    int t = threadIdx.x;
    int v = (t < nb) ? bsums[t] : 0;
    s[t] = v;
    __syncthreads();
    for (int off = 1; off < 512; off <<= 1) {
        int a = (t >= off) ? s[t - off] : 0;
        __syncthreads();
        s[t] += a;
        __syncthreads();
    }
    if (t < nb) bsums[t] = s[t] - v;
    if (t == 0) row_ptr[n] = e;
}

__global__ void scan_emit(const int* __restrict__ counts, const int* __restrict__ boffs,
                          int* __restrict__ row_ptr, int* __restrict__ cursor,
                          float* __restrict__ dinv, float* __restrict__ rdeg, int n) {
    __shared__ int red[SCAN_T];
    int t = threadIdx.x;
    int base = blockIdx.x * SCAN_CHUNK + t * SCAN_I;
    int c[SCAN_I];
    int s = 0;
#pragma unroll
    for (int k = 0; k < SCAN_I; ++k) { int i = base + k; c[k] = (i < n) ? counts[i] : 0; s += c[k]; }
    red[t] = s;
    __syncthreads();
    for (int off = 1; off < SCAN_T; off <<= 1) {
        int a = (t >= off) ? red[t - off] : 0;
        __syncthreads();
        red[t] += a;
        __syncthreads();
    }
    int run = boffs[blockIdx.x] + red[t] - s;
#pragma unroll
    for (int k = 0; k < SCAN_I; ++k) {
        int i = base + k;
        if (i < n) {
            row_ptr[i] = run;
            cursor[i]  = run;
            float d = (float)(c[k] + 1);
            dinv[i] = rsqrtf(d);
            rdeg[i] = sqrtf(d);
            run += c[k];
        }
    }
}

// zh = fp16(dinv * x), vectorized; zero row n of zh and z1h (tail-clamp target).
__global__ void cast_z(const float* __restrict__ x, const float* __restrict__ dinv,
                       __half* __restrict__ zh, __half* __restrict__ z1h, int n) {
    int i = blockIdx.x * blockDim.x + threadIdx.x;   // one group of 4 features
    int total = n * 16;
    if (i < total) {
        float4 v = reinterpret_cast<const float4*>(x)[i];
        float dv = dinv[i >> 4];
        __half2 a, b2;
        a.x  = __float2half(v.x * dv); a.y  = __float2half(v.y * dv);
        b2.x = __float2half(v.z * dv); b2.y = __float2half(v.w * dv);
        reinterpret_cast<__half2*>(zh)[2 * i]     = a;
        reinterpret_cast<__half2*>(zh)[2 * i + 1] = b2;
    } else if (i < total + 16) {
        __half2 z; z.x = __float2half(0.f); z.y = __float2half(0.f);
        reinterpret_cast<__half2*>(zh)[2 * i]      = z;
        reinterpret_cast<__half2*>(zh)[2 * i + 1]  = z;
        reinterpret_cast<__half2*>(z1h)[2 * i]     = z;
        reinterpret_cast<__half2*>(z1h)[2 * i + 1] = z;
    }
}

__global__ void fill_kernel(const int* __restrict__ src, const int* __restrict__ dst,
                            int* __restrict__ cursor, int* __restrict__ col, int e) {
    int i = blockIdx.x * blockDim.x + threadIdx.x;
    if (i >= e) return;
    int pos = atomicAdd(&cursor[dst[i]], 1);
    col[pos] = src[i];
}

// Non-temporal fp16 load (no L1 allocate).
__device__ __forceinline__ float ld_nt_half(const __half* p) {
    unsigned short u = __builtin_nontemporal_load(reinterpret_cast<const unsigned short*>(p));
    __half_raw hr; hr.x = u;
    return __half2float((__half)hr);
}

// Batch-16 pipelined gather of fp16 rows (64 lanes = one 128B line per edge).
// Tail lanes clamp to the all-zero row `nzero`.
__device__ __forceinline__ float spmm_row(const __half* __restrict__ zh,
                                          const int* __restrict__ col,
                                          int beg, int end, int lane, int nzero) {
    float acc = 0.f;
    for (int j = beg; j < end; j += BATCH) {
        int c[BATCH];
#pragma unroll
        for (int k = 0; k < BATCH; ++k) {
            int jj = j + k;
            int cc = col[min(jj, end - 1)];            // unconditional in-bounds load
            c[k] = (jj < end) ? cc : nzero;
        }
        float xv[BATCH];
#pragma unroll
        for (int k = 0; k < BATCH; ++k)
            xv[k] = ld_nt_half(zh + (size_t)(unsigned)c[k] * 64u + (unsigned)lane);
#pragma unroll
        for (int k = 0; k < BATCH; ++k) acc += xv[k];
    }
    return acc;
}

// Step 1: zh -> z1h (= dinv * x1). xi recovered as zh[i]*rdeg[i].
__global__ void spmm1_kernel(const __half* __restrict__ zh, __half* __restrict__ z1h,
                             const int* __restrict__ row_ptr, const int* __restrict__ col,
                             const float* __restrict__ dinv, const float* __restrict__ rdeg,
                             int n, float delta) {
    int node = blockIdx.x * (blockDim.x >> 6) + (threadIdx.x >> 6);
    int lane = threadIdx.x & 63;
    if (node >= n) return;
    size_t idx = (size_t)node * 64 + lane;
    float dv = dinv[node], rd = rdeg[node];
    float zf = __half2float(zh[idx]);                   // zf = dv * xi
    float acc = spmm_row(zh, col, row_ptr[node], row_ptr[node + 1], lane, n);
    float x1 = (1.f - delta) * (zf * rd) + delta * dv * (zf + acc);
    z1h[idx] = __float2half(dv * x1);
}

// Step 2 SpMM + y = x2 @ W + b (shfl-broadcast row, W staged in LDS).
__global__ void spmm2_gemm_kernel(const __half* __restrict__ z1h, float* __restrict__ y,
                                  const int* __restrict__ row_ptr, const int* __restrict__ col,
                                  const float* __restrict__ dinv, const float* __restrict__ rdeg,
                                  const float* __restrict__ W, const float* __restrict__ b,
                                  int n, float delta) {
    __shared__ float Ws[64 * 64];
    __shared__ float bs[64];
    for (int i = threadIdx.x; i < 64 * 64; i += blockDim.x) Ws[i] = W[i];
    if (threadIdx.x < 64) bs[threadIdx.x] = b[threadIdx.x];
    __syncthreads();
    int node = blockIdx.x * (blockDim.x >> 6) + (threadIdx.x >> 6);
    int lane = threadIdx.x & 63;
    if (node >= n) return;
    size_t idx = (size_t)node * 64 + lane;
    float dv = dinv[node], rd = rdeg[node];
    float zf = __half2float(z1h[idx]);                  // zf = dv * x1
    float acc = spmm_row(z1h, col, row_ptr[node], row_ptr[node + 1], lane, n);
    float res = (1.f - delta) * (zf * rd) + delta * dv * (zf + acc);
    float o = bs[lane];
#pragma unroll
    for (int k = 0; k < 64; ++k) {
        o += __shfl(res, k) * Ws[k * 64 + lane];   // stride-1 across lanes: conflict-free
    }
    y[idx] = o;
}

extern "C" void kernel_launch(void* const* d_in, const int* in_sizes, int n_in,
                              void* d_out, int out_size, void* d_ws, size_t ws_size,
                              hipStream_t stream) {
    const float* x  = (const float*)d_in[0];
    const int*   ei = (const int*)d_in[1];   // [2, E]: src then dst
    const float* W  = (const float*)d_in[2];
    const float* b  = (const float*)d_in[3];
    float* out = (float*)d_out;

    const int N = in_sizes[0] / 64;
    const int E = in_sizes[1] / 2;
    const float delta = (float)(5.27 / 2.0);

    char* p = (char*)d_ws;
    __half* zh   = (__half*)p;  p += (size_t)(N + 1) * 64 * sizeof(__half);
    __half* z1h  = (__half*)p;  p += (size_t)(N + 1) * 64 * sizeof(__half);
    int*   col   = (int*)p;     p += ((size_t)E + 64) * sizeof(int);
    float* dinv  = (float*)p;   p += (size_t)N * sizeof(float);
    float* rdeg  = (float*)p;   p += (size_t)N * sizeof(float);
    int*   counts= (int*)p;     p += (size_t)N * sizeof(int);
    int*   rowp  = (int*)p;     p += (size_t)(N + 4) * sizeof(int);
    int*   cursor= (int*)p;     p += (size_t)N * sizeof(int);
    int*   bsums = (int*)p;     p += 512 * sizeof(int);

    hipMemsetAsync(counts, 0, (size_t)N * sizeof(int), stream);

    int grid_e = (E + TPB - 1) / TPB;
    int grid_n = (N + (TPB / 64) - 1) / (TPB / 64);
    int nb_scan = (N + SCAN_CHUNK - 1) / SCAN_CHUNK;
    int grid_c = (N * 16 + 16 + TPB - 1) / TPB;

    count_kernel<<<grid_e, TPB, 0, stream>>>(ei + E, counts, E);
    scan_partials<<<nb_scan, SCAN_T, 0, stream>>>(counts, bsums, N);
    scan_bsums<<<1, 512, 0, stream>>>(bsums, nb_scan, rowp, N, E);
    scan_emit<<<nb_scan, SCAN_T, 0, stream>>>(counts, bsums, rowp, cursor, dinv, rdeg, N);
    cast_z<<<grid_c, TPB, 0, stream>>>(x, dinv, zh, z1h, N);
    fill_kernel<<<grid_e, TPB, 0, stream>>>(ei, ei + E, cursor, col, E);

    spmm1_kernel<<<grid_n, TPB, 0, stream>>>(zh, z1h, rowp, col, dinv, rdeg, N, delta);
    spmm2_gemm_kernel<<<grid_n, TPB, 0, stream>>>(z1h, out, rowp, col, dinv, rdeg, W, b, N, delta);
}

// Round 7
// 373.591 us; speedup vs baseline: 1.2499x; 1.1058x over previous
//
#include <hip/hip_runtime.h>
#include <hip/hip_fp16.h>

// DGConv: K=2 diffusion steps of x <- (1-d)x + d * (D^-1/2 (A+I) D^-1/2) x, then x @ W + b.
// N=100000, E=1600000, D=64. delta = 5.27/2 = 2.635.
//
// z = dinv (.) x stored fp16: row = 128B = one cache line. SpMM layout: TWO nodes per
// wave (lanes 0-31 node A, 32-63 node B), half2 per lane -> each gather instruction
// services 2 edges. Column indices are loaded vectorized (32/lane-chunk) and broadcast
// via shfl. xi is recovered as z[i]*rdeg[i], so only z-streams are kept.

#define TPB 256
#define SCAN_T 256
#define SCAN_I 4
#define SCAN_CHUNK (SCAN_T * SCAN_I)

__global__ void count_kernel(const int* __restrict__ dst, int* __restrict__ counts, int e) {
    int i = blockIdx.x * blockDim.x + threadIdx.x;
    if (i < e) atomicAdd(&counts[dst[i]], 1);
}

__global__ void scan_partials(const int* __restrict__ counts, int* __restrict__ bsums, int n) {
    __shared__ int red[SCAN_T];
    int t = threadIdx.x;
    int base = blockIdx.x * SCAN_CHUNK + t * SCAN_I;
    int s = 0;
#pragma unroll
    for (int k = 0; k < SCAN_I; ++k) { int i = base + k; if (i < n) s += counts[i]; }
    red[t] = s;
    __syncthreads();
    for (int off = SCAN_T / 2; off > 0; off >>= 1) {
        if (t < off) red[t] += red[t + off];
        __syncthreads();
    }
    if (t == 0) bsums[blockIdx.x] = red[0];
}

__global__ void scan_bsums(int* __restrict__ bsums, int nb, int* __restrict__ row_ptr,
                           int n, int e) {
    __shared__ int s[512];
    int t = threadIdx.x;
    int v = (t < nb) ? bsums[t] : 0;
    s[t] = v;
    __syncthreads();
    for (int off = 1; off < 512; off <<= 1) {
        int a = (t >= off) ? s[t - off] : 0;
        __syncthreads();
        s[t] += a;
        __syncthreads();
    }
    if (t < nb) bsums[t] = s[t] - v;
    if (t == 0) row_ptr[n] = e;
}

__global__ void scan_emit(const int* __restrict__ counts, const int* __restrict__ boffs,
                          int* __restrict__ row_ptr, int* __restrict__ cursor,
                          float* __restrict__ dinv, float* __restrict__ rdeg, int n) {
    __shared__ int red[SCAN_T];
    int t = threadIdx.x;
    int base = blockIdx.x * SCAN_CHUNK + t * SCAN_I;
    int c[SCAN_I];
    int s = 0;
#pragma unroll
    for (int k = 0; k < SCAN_I; ++k) { int i = base + k; c[k] = (i < n) ? counts[i] : 0; s += c[k]; }
    red[t] = s;
    __syncthreads();
    for (int off = 1; off < SCAN_T; off <<= 1) {
        int a = (t >= off) ? red[t - off] : 0;
        __syncthreads();
        red[t] += a;
        __syncthreads();
    }
    int run = boffs[blockIdx.x] + red[t] - s;
#pragma unroll
    for (int k = 0; k < SCAN_I; ++k) {
        int i = base + k;
        if (i < n) {
            row_ptr[i] = run;
            cursor[i]  = run;
            float d = (float)(c[k] + 1);
            dinv[i] = rsqrtf(d);
            rdeg[i] = sqrtf(d);
            run += c[k];
        }
    }
}

// zh = fp16(dinv * x), vectorized; zero row n of zh and z1h (tail-clamp target).
__global__ void cast_z(const float* __restrict__ x, const float* __restrict__ dinv,
                       __half* __restrict__ zh, __half* __restrict__ z1h, int n) {
    int i = blockIdx.x * blockDim.x + threadIdx.x;   // one group of 4 features
    int total = n * 16;
    if (i < total) {
        float4 v = reinterpret_cast<const float4*>(x)[i];
        float dv = dinv[i >> 4];
        __half2 a, b2;
        a.x  = __float2half(v.x * dv); a.y  = __float2half(v.y * dv);
        b2.x = __float2half(v.z * dv); b2.y = __float2half(v.w * dv);
        reinterpret_cast<__half2*>(zh)[2 * i]     = a;
        reinterpret_cast<__half2*>(zh)[2 * i + 1] = b2;
    } else if (i < total + 16) {
        __half2 z; z.x = __float2half(0.f); z.y = __float2half(0.f);
        reinterpret_cast<__half2*>(zh)[2 * i]      = z;
        reinterpret_cast<__half2*>(zh)[2 * i + 1]  = z;
        reinterpret_cast<__half2*>(z1h)[2 * i]     = z;
        reinterpret_cast<__half2*>(z1h)[2 * i + 1] = z;
    }
}

__global__ void fill_kernel(const int* __restrict__ src, const int* __restrict__ dst,
                            int* __restrict__ cursor, int* __restrict__ col, int e) {
    int i = blockIdx.x * blockDim.x + threadIdx.x;
    if (i >= e) return;
    int pos = atomicAdd(&cursor[dst[i]], 1);
    col[pos] = src[i];
}

// Pair-of-nodes gather. Lanes 0-31: node A, lanes 32-63: node B; lane m holds
// features (2m, 2m+1) as half2. Per 32-edge chunk: ONE vectorized col load
// (lane m loads its node's col[beg+base+m], clamped to zero-row beyond degree),
// then groups of 8 gather instructions, indices broadcast via shfl.
__device__ __forceinline__ float2 pair_gather(const __half* __restrict__ zh,
                                              const int* __restrict__ col,
                                              int myb, int mye, int lim,
                                              int sub, int m, int nzero) {
    float a0 = 0.f, a1 = 0.f;
    for (int base = 0; base < lim; base += 32) {
        int j = myb + base + m;
        int idx = (mye > myb) ? min(j, mye - 1) : 0;
        int cc = col[idx];                       // 1 VMEM instr per 64 edges
        int cv = (j < mye) ? cc : nzero;         // clamp beyond own degree
        int gl = min(32, lim - base);
        for (int k = 0; k < gl; k += 8) {        // wave-uniform trip
            float2 f[8];
#pragma unroll
            for (int u = 0; u < 8; ++u) {
                int src = __shfl(cv, (sub << 5) + k + u);   // broadcast within half
                __half2 h = *reinterpret_cast<const __half2*>(
                    zh + (size_t)(unsigned)src * 64u + 2u * (unsigned)m);
                f[u] = __half22float2(h);
            }
#pragma unroll
            for (int u = 0; u < 8; ++u) { a0 += f[u].x; a1 += f[u].y; }
        }
    }
    return make_float2(a0, a1);
}

// Step 1: zh -> z1h (= dinv * x1). xi recovered as zh[i]*rdeg[i].
__global__ void spmm1_kernel(const __half* __restrict__ zh, __half* __restrict__ z1h,
                             const int* __restrict__ row_ptr, const int* __restrict__ col,
                             const float* __restrict__ dinv, const float* __restrict__ rdeg,
                             int n, float delta) {
    int pair = blockIdx.x * (blockDim.x >> 6) + (threadIdx.x >> 6);
    int lane = threadIdx.x & 63;
    if (2 * pair >= n) return;
    int sub = lane >> 5, m = lane & 31;
    int node = 2 * pair + sub;
    int nc = min(node, n - 1);
    int myb = row_ptr[nc], mye = row_ptr[nc + 1];
    if (node >= n) { myb = 0; mye = 0; }           // dummy B for odd n
    int len = mye - myb;
    int lim = max(len, __shfl_xor(len, 32));       // pair-max trip count
    float dv = dinv[nc], rd = rdeg[nc];
    float2 acc = pair_gather(zh, col, myb, mye, lim, sub, m, n);
    __half2 zp = *reinterpret_cast<const __half2*>(zh + (size_t)nc * 64 + 2 * m);
    float2 zf = __half22float2(zp);                // zf = dv * xi
    float x1x = (1.f - delta) * (zf.x * rd) + delta * dv * (zf.x + acc.x);
    float x1y = (1.f - delta) * (zf.y * rd) + delta * dv * (zf.y + acc.y);
    if (node < n) {
        __half2 o; o.x = __float2half(dv * x1x); o.y = __float2half(dv * x1y);
        *reinterpret_cast<__half2*>(z1h + (size_t)node * 64 + 2 * m) = o;
    }
}

// Step 2 SpMM + y = x2 @ W + b. Pair layout; 2 outputs/lane; float2 LDS W reads.
__global__ void spmm2_gemm_kernel(const __half* __restrict__ z1h, float* __restrict__ y,
                                  const int* __restrict__ row_ptr, const int* __restrict__ col,
                                  const float* __restrict__ dinv, const float* __restrict__ rdeg,
                                  const float* __restrict__ W, const float* __restrict__ b,
                                  int n, float delta) {
    __shared__ float Ws[64 * 64];
    __shared__ float bs[64];
    for (int i = threadIdx.x; i < 64 * 64; i += blockDim.x) Ws[i] = W[i];
    if (threadIdx.x < 64) bs[threadIdx.x] = b[threadIdx.x];
    __syncthreads();
    int pair = blockIdx.x * (blockDim.x >> 6) + (threadIdx.x >> 6);
    int lane = threadIdx.x & 63;
    if (2 * pair >= n) return;
    int sub = lane >> 5, m = lane & 31;
    int node = 2 * pair + sub;
    int nc = min(node, n - 1);
    int myb = row_ptr[nc], mye = row_ptr[nc + 1];
    if (node >= n) { myb = 0; mye = 0; }
    int len = mye - myb;
    int lim = max(len, __shfl_xor(len, 32));
    float dv = dinv[nc], rd = rdeg[nc];
    float2 acc = pair_gather(z1h, col, myb, mye, lim, sub, m, n);
    __half2 zp = *reinterpret_cast<const __half2*>(z1h + (size_t)nc * 64 + 2 * m);
    float2 zf = __half22float2(zp);                // zf = dv * x1
    float rx = (1.f - delta) * (zf.x * rd) + delta * dv * (zf.x + acc.x);  // res[2m]
    float ry = (1.f - delta) * (zf.y * rd) + delta * dv * (zf.y + acc.y);  // res[2m+1]
    float o0 = bs[2 * m], o1 = bs[2 * m + 1];
#pragma unroll
    for (int q = 0; q < 32; ++q) {
        float ax = __shfl(rx, (sub << 5) + q);     // res[2q] of own node
        float ay = __shfl(ry, (sub << 5) + q);     // res[2q+1]
        float2 w0 = *reinterpret_cast<const float2*>(&Ws[(2 * q) * 64 + 2 * m]);
        float2 w1 = *reinterpret_cast<const float2*>(&Ws[(2 * q + 1) * 64 + 2 * m]);
        o0 = fmaf(ax, w0.x, o0); o0 = fmaf(ay, w1.x, o0);
        o1 = fmaf(ax, w0.y, o1); o1 = fmaf(ay, w1.y, o1);
    }
    if (node < n) {
        *reinterpret_cast<float2*>(y + (size_t)node * 64 + 2 * m) = make_float2(o0, o1);
    }
}

extern "C" void kernel_launch(void* const* d_in, const int* in_sizes, int n_in,
                              void* d_out, int out_size, void* d_ws, size_t ws_size,
                              hipStream_t stream) {
    const float* x  = (const float*)d_in[0];
    const int*   ei = (const int*)d_in[1];   // [2, E]: src then dst
    const float* W  = (const float*)d_in[2];
    const float* b  = (const float*)d_in[3];
    float* out = (float*)d_out;

    const int N = in_sizes[0] / 64;
    const int E = in_sizes[1] / 2;
    const float delta = (float)(5.27 / 2.0);

    char* p = (char*)d_ws;
    __half* zh   = (__half*)p;  p += (size_t)(N + 1) * 64 * sizeof(__half);
    __half* z1h  = (__half*)p;  p += (size_t)(N + 1) * 64 * sizeof(__half);
    int*   col   = (int*)p;     p += ((size_t)E + 64) * sizeof(int);
    float* dinv  = (float*)p;   p += (size_t)N * sizeof(float);
    float* rdeg  = (float*)p;   p += (size_t)N * sizeof(float);
    int*   counts= (int*)p;     p += (size_t)N * sizeof(int);
    int*   rowp  = (int*)p;     p += (size_t)(N + 4) * sizeof(int);
    int*   cursor= (int*)p;     p += (size_t)N * sizeof(int);
    int*   bsums = (int*)p;     p += 512 * sizeof(int);

    hipMemsetAsync(counts, 0, (size_t)N * sizeof(int), stream);

    int grid_e = (E + TPB - 1) / TPB;
    int nb_scan = (N + SCAN_CHUNK - 1) / SCAN_CHUNK;
    int grid_c = (N * 16 + 16 + TPB - 1) / TPB;
    int pairs = (N + 1) / 2;
    int grid_p = (pairs + (TPB / 64) - 1) / (TPB / 64);

    count_kernel<<<grid_e, TPB, 0, stream>>>(ei + E, counts, E);
    scan_partials<<<nb_scan, SCAN_T, 0, stream>>>(counts, bsums, N);
    scan_bsums<<<1, 512, 0, stream>>>(bsums, nb_scan, rowp, N, E);
    scan_emit<<<nb_scan, SCAN_T, 0, stream>>>(counts, bsums, rowp, cursor, dinv, rdeg, N);
    cast_z<<<grid_c, TPB, 0, stream>>>(x, dinv, zh, z1h, N);
    fill_kernel<<<grid_e, TPB, 0, stream>>>(ei, ei + E, cursor, col, E);

    spmm1_kernel<<<grid_p, TPB, 0, stream>>>(zh, z1h, rowp, col, dinv, rdeg, N, delta);
    spmm2_gemm_kernel<<<grid_p, TPB, 0, stream>>>(z1h, out, rowp, col, dinv, rdeg, W, b, N, delta);
}